// Round 1
// baseline (328.022 us; speedup 1.0000x reference)
//
#include <hip/hip_runtime.h>
#include <cstdint>
#include <cstddef>

// ---------------- workspace layout (bytes) ----------------
// Wp   : packed gate-interleaved weight, bf16, 768x1024 (4 cb x 32 kb tiles, 192x32) = 1,572,864
// Fp   : packed fco_w, bf16, 256x256 (2 nb x 8 kb tiles, 128x32)                     =   131,072
// bp   : permuted bias (c = h*3+g), f32, 768
// hvp  : packed hidden vector, bf16, 32768x256 (256 mb x 8 kb tiles, 128x32)
#define WS_WP   0
#define WS_FCO  1572864
#define WS_BP   1703936
#define WS_HVP  1707008

typedef __attribute__((ext_vector_type(8))) __bf16 bf16x8;
typedef __attribute__((ext_vector_type(4))) __bf16 bf16x4;
typedef __attribute__((ext_vector_type(4))) float floatx4;

__device__ __forceinline__ unsigned short f2bf(float f) {
  unsigned int u = __builtin_bit_cast(unsigned int, f);
  u += 0x7fffu + ((u >> 16) & 1u);   // RNE
  return (unsigned short)(u >> 16);
}

__device__ __forceinline__ float sigmf(float z) {
  return __builtin_amdgcn_rcpf(1.f + __expf(-z));
}
__device__ __forceinline__ float tanh_(float z) {
  return 1.f - 2.f * __builtin_amdgcn_rcpf(1.f + __expf(2.f * z));
}

__device__ __forceinline__ void gld16(const void* g, void* l) {
  __builtin_amdgcn_global_load_lds(
      (const __attribute__((address_space(1))) unsigned int*)g,
      (__attribute__((address_space(3))) unsigned int*)l, 16, 0, 0);
}

// ---------------- merged pack kernel (unchanged) ----------------
__global__ __launch_bounds__(256) void pack_k(
    const float* __restrict__ wr, const float* __restrict__ wi,
    const float* __restrict__ wj, const float* __restrict__ wk,
    const float* __restrict__ bx, const float* __restrict__ fw,
    unsigned short* __restrict__ Wp, unsigned short* __restrict__ Fp,
    float* __restrict__ bp) {
  int t = threadIdx.x;
  if (blockIdx.x < 384) {
    int gpp = blockIdx.x >> 7;        // 0..2 -> gates {input,output,cell}
    int oct = blockIdx.x & 127;       // f-octet
    int gp = gpp + 1;                 // skip dead forget gate
    int h = t;                        // 0..255, lane-contiguous
    int hb = h >> 6, hr = h & 63;     // hb wave-uniform
    int f0 = oct << 3;
    int fb = f0 >> 8, fr0 = f0 & 255;
    const int   comp_t[4][4] = {{0,1,2,3},{1,0,3,2},{2,3,0,1},{3,2,1,0}};
    const float sign_t[4][4] = {{1.f,-1.f,-1.f,-1.f},{1.f,1.f,-1.f,1.f},
                                {1.f,1.f,1.f,-1.f},{1.f,-1.f,1.f,1.f}};
    const float* srcs[4] = {wr, wi, wj, wk};
    const float* s = srcs[comp_t[hb][fb]] + ((size_t)((gp << 8) + fr0)) * 64 + hr;
    float sg = sign_t[hb][fb];
    unsigned short v[8];
#pragma unroll
    for (int j = 0; j < 8; ++j) v[j] = f2bf(sg * s[(size_t)j * 64]);
    int c = h * 3 + gpp;
    int cb = c / 192, nl = c % 192;
    int kb = oct >> 2, q = oct & 3;
    int idx16 = (nl << 2) + (q ^ ((nl >> 1) & 3));
    uint4 val = make_uint4(
        (unsigned)v[0] | ((unsigned)v[1] << 16), (unsigned)v[2] | ((unsigned)v[3] << 16),
        (unsigned)v[4] | ((unsigned)v[5] << 16), (unsigned)v[6] | ((unsigned)v[7] << 16));
    *(uint4*)(Wp + (size_t)(cb * 32 + kb) * 6144 + idx16 * 8) = val;
    if (oct == 0) bp[c] = bx[(gp << 8) + h];
  } else {
    int oct = blockIdx.x - 384;       // k-octet 0..31
    int n = t;
    int k0 = oct << 3;
    unsigned short v[8];
#pragma unroll
    for (int j = 0; j < 8; ++j) v[j] = f2bf(fw[(size_t)(k0 + j) * 256 + n]);
    int nb = n >> 7, nl = n & 127, kb = oct >> 2, q = oct & 3;
    int idx16 = (nl << 2) + (q ^ ((nl >> 1) & 3));
    uint4 val = make_uint4(
        (unsigned)v[0] | ((unsigned)v[1] << 16), (unsigned)v[2] | ((unsigned)v[3] << 16),
        (unsigned)v[4] | ((unsigned)v[5] << 16), (unsigned)v[6] | ((unsigned)v[7] << 16));
    *(uint4*)(Fp + (size_t)((nb << 3) + kb) * 4096 + idx16 * 8) = val;
  }
}

// ---------------- GEMM1 + fused LSTM gates ----------------
// Tile 128x192, 4 waves of 64x96, BK=32, acc[4][6].
// THEORY (this revision): old version was LDS-pipe bound (A staged+read as fp32:
// 168 KB LDS traffic per block-K-step vs ~230 cyc of MFMA). Now A is converted
// fp32->bf16 through registers (global float4 -> cvt -> ds_write_b64) into the
// same packed XOR-swizzled slot layout as B, halving A bytes on both LDS sides
// (block-step traffic 168 KB -> 60 KB) and removing the per-fragment cvt.
// LDS: 2 x 20 KB buffers (A 8K bf16 + B 12K bf16); epilogue 4 passes of 32 rows.
// Staging loads issue right after the barrier; the ra->LDS write (and its
// counted vmcnt wait) lands after the 24-MFMA compute phase, preserving the
// double-buffer latency skew.
__global__ __launch_bounds__(256, 2) void gemm1_k(
    const float* __restrict__ x, const unsigned short* __restrict__ Wp,
    const float* __restrict__ bp, unsigned short* __restrict__ hvp) {
  __shared__ char smem[40960];                  // 2 x (A bf16 8K + B bf16 12K); epi 32x201 f32
  float* zep = (float*)smem;

  const int t = threadIdx.x;
  const int lane = t & 63, wid = t >> 6;
  const int wm = wid >> 1, wn = wid & 1;
  const int lrow = lane & 15, q = lane >> 4;
  const int rowt = blockIdx.x;                  // 0..255 (fast dim: W stays L2-hot)
  const int cby = blockIdx.y;                   // 0..3, 192 interleaved cols (64 h)
  const int row0 = rowt * 128;
  const float* xbase = x + (size_t)row0 * 1024;
  const unsigned short* wpb = Wp + (size_t)cby * 32 * 6144;

  // A staging mapping: thread t handles, for i in 0..3, the float4 at
  // row (i*32 + (t>>3)), k-quad (t&7). Per global-load instruction each 8-lane
  // group covers one full 128B row segment (perfect coalescing).
  const int sr = t >> 3, skq = t & 7;
  const int sq8 = skq >> 1, shalf = skq & 1;

  floatx4 acc[4][6];
#pragma unroll
  for (int i = 0; i < 4; ++i)
#pragma unroll
    for (int j = 0; j < 6; ++j) acc[i][j] = (floatx4){0.f, 0.f, 0.f, 0.f};

#define STAGE_B(buf, kt)                                                      \
  {                                                                           \
    unsigned short* sBs_ = (unsigned short*)(smem + (buf) * 20480 + 8192);    \
    const unsigned short* bt_ = wpb + (size_t)(kt) * 6144;                    \
    _Pragma("unroll")                                                         \
    for (int i_ = 0; i_ < 3; ++i_) {                                          \
      int s_ = t + i_ * 256;                                                  \
      gld16(bt_ + s_ * 8, sBs_ + s_ * 8);                                     \
    }                                                                         \
  }
#define LOAD_A(ra, kt)                                                        \
  {                                                                           \
    const float* ab_ = xbase + (kt) * 32 + skq * 4;                           \
    _Pragma("unroll")                                                         \
    for (int i_ = 0; i_ < 4; ++i_)                                            \
      ra[i_] = *(const float4*)(ab_ + (size_t)(i_ * 32 + sr) * 1024);         \
  }
#define WRITE_A(ra, buf)                                                      \
  {                                                                           \
    unsigned short* sAs_ = (unsigned short*)(smem + (buf) * 20480);           \
    _Pragma("unroll")                                                         \
    for (int i_ = 0; i_ < 4; ++i_) {                                          \
      int m_ = i_ * 32 + sr;                                                  \
      int slot_ = (m_ << 2) + (sq8 ^ ((m_ >> 1) & 3));                        \
      bf16x4 v_;                                                              \
      v_[0] = (__bf16)ra[i_].x; v_[1] = (__bf16)ra[i_].y;                     \
      v_[2] = (__bf16)ra[i_].z; v_[3] = (__bf16)ra[i_].w;                     \
      *(bf16x4*)(sAs_ + slot_ * 8 + shalf * 4) = v_;                          \
    }                                                                         \
  }

  {
    float4 r0[4];
    LOAD_A(r0, 0)
    STAGE_B(0, 0)
    WRITE_A(r0, 0)
  }
  float4 ra[4];
  for (int kt = 0; kt < 32; ++kt) {
    __syncthreads();                            // buf(kt) staged; prior reads done
    if (kt < 31) {
      LOAD_A(ra, kt + 1)                        // global->reg, waited only at WRITE_A
      STAGE_B((kt + 1) & 1, kt + 1)             // async global->LDS (vmcnt)
    }
    const unsigned short* sA = (const unsigned short*)(smem + (kt & 1) * 20480);
    const unsigned short* sB = sA + 4096;       // +8192 bytes
    bf16x8 af[4], bf[6];
#pragma unroll
    for (int mt = 0; mt < 4; ++mt) {
      int m = wm * 64 + mt * 16 + lrow;
      int slot = (m << 2) + (q ^ ((m >> 1) & 3));
      af[mt] = *(const bf16x8*)(const void*)(sA + slot * 8);
    }
#pragma unroll
    for (int nt = 0; nt < 6; ++nt) {
      int n = wn * 96 + nt * 16 + lrow;
      int off16 = (n << 2) + (q ^ ((n >> 1) & 3));
      bf[nt] = *(const bf16x8*)(const void*)(sB + off16 * 8);
    }
#pragma unroll
    for (int mt = 0; mt < 4; ++mt)
#pragma unroll
      for (int nt = 0; nt < 6; ++nt)
        acc[mt][nt] = __builtin_amdgcn_mfma_f32_16x16x32_bf16(af[mt], bf[nt], acc[mt][nt], 0, 0, 0);
    if (kt < 31) WRITE_A(ra, (kt + 1) & 1)      // cvt + ds_write into other buffer
  }
#undef STAGE_B
#undef LOAD_A
#undef WRITE_A
  __syncthreads();                              // all K-loop LDS reads done before zep reuse

  // Epilogue: 4 passes of 32 rows via LDS (pitch 201 f32), fused gates,
  // hv stored in gemm2's packed-swizzled tile layout.
  const float* bp0 = bp + cby * 192;
  const int er = t >> 3, oc = t & 7;
#pragma unroll
  for (int pass = 0; pass < 4; ++pass) {
    if (wm == (pass >> 1)) {
      int mtb = (pass & 1) * 2;
#pragma unroll
      for (int mi = 0; mi < 2; ++mi)
#pragma unroll
        for (int nt = 0; nt < 6; ++nt)
#pragma unroll
          for (int r = 0; r < 4; ++r)
            zep[(mi * 16 + q * 4 + r) * 201 + wn * 96 + nt * 16 + lrow] = acc[mtb + mi][nt][r];
    }
    __syncthreads();
    {
      int ml = pass * 32 + er;                  // local row 0..127
      unsigned short v[8];
#pragma unroll
      for (int j = 0; j < 8; ++j) {
        int hl = oc * 8 + j;                    // 0..63 local h
        float zi = zep[er * 201 + hl * 3 + 0] + bp0[hl * 3 + 0];
        float zo = zep[er * 201 + hl * 3 + 1] + bp0[hl * 3 + 1];
        float zc = zep[er * 201 + hl * 3 + 2] + bp0[hl * 3 + 2];
        float it = sigmf(zi);
        float ot = sigmf(zo);
        float cc = it * tanh_(zc);
        v[j] = f2bf(ot * tanh_(cc));
      }
      int ktile = cby * 2 + (oc >> 2), qq = oc & 3;
      int idx16 = (ml << 2) + (qq ^ ((ml >> 1) & 3));
      uint4 val = make_uint4(
          (unsigned)v[0] | ((unsigned)v[1] << 16), (unsigned)v[2] | ((unsigned)v[3] << 16),
          (unsigned)v[4] | ((unsigned)v[5] << 16), (unsigned)v[6] | ((unsigned)v[7] << 16));
      *(uint4*)(hvp + (size_t)(rowt * 8 + ktile) * 4096 + idx16 * 8) = val;
    }
    __syncthreads();
  }
}

// ---------------- GEMM2: out = hv @ fco_w + fco_b (fp32 output, unchanged) ----------------
__global__ __launch_bounds__(256, 4) void gemm2_k(
    const unsigned short* __restrict__ hvp, const unsigned short* __restrict__ Fp,
    const float* __restrict__ fcob, float* __restrict__ out) {
  __shared__ unsigned short sB[32768];          // 64 KB: 8 k-tiles of 128x32
  const int t = threadIdx.x;
  const int lane = t & 63, wid = t >> 6;
  const int wm = wid >> 1, wn = wid & 1;
  const int lrow = lane & 15, q = lane >> 4;
  const int mb = blockIdx.x, nb = blockIdx.y;

  const unsigned short* fpb = Fp + (size_t)nb * 32768;
#pragma unroll
  for (int i = 0; i < 16; ++i) gld16(fpb + (t + i * 256) * 8, sB + (t + i * 256) * 8);

  floatx4 acc[4][4];
#pragma unroll
  for (int i = 0; i < 4; ++i)
#pragma unroll
    for (int j = 0; j < 4; ++j) acc[i][j] = (floatx4){0.f, 0.f, 0.f, 0.f};
  __syncthreads();

#pragma unroll
  for (int kt = 0; kt < 8; ++kt) {
    const unsigned short* at_ = hvp + (size_t)(mb * 8 + kt) * 4096;
    bf16x8 af[4], bf[4];
#pragma unroll
    for (int mt = 0; mt < 4; ++mt) {
      int m = wm * 64 + mt * 16 + lrow;
      int o = (m << 2) + (q ^ ((m >> 1) & 3));
      af[mt] = *(const bf16x8*)(const void*)(at_ + o * 8);    // global, coalesced
    }
#pragma unroll
    for (int nt = 0; nt < 4; ++nt) {
      int n = wn * 64 + nt * 16 + lrow;
      int o = (n << 2) + (q ^ ((n >> 1) & 3));
      bf[nt] = *(const bf16x8*)(const void*)(sB + kt * 4096 + o * 8);
    }
#pragma unroll
    for (int mt = 0; mt < 4; ++mt)
#pragma unroll
      for (int nt = 0; nt < 4; ++nt)
        acc[mt][nt] = __builtin_amdgcn_mfma_f32_16x16x32_bf16(af[mt], bf[nt], acc[mt][nt], 0, 0, 0);
  }
#pragma unroll
  for (int nt = 0; nt < 4; ++nt) {
    int colg = nb * 128 + wn * 64 + nt * 16 + lrow;
    float bias = fcob[colg];
#pragma unroll
    for (int mt = 0; mt < 4; ++mt) {
      int rowg = mb * 128 + wm * 64 + mt * 16 + q * 4;
#pragma unroll
      for (int r = 0; r < 4; ++r)
        out[(size_t)(rowg + r) * 256 + colg] = acc[mt][nt][r] + bias;
    }
  }
}

extern "C" void kernel_launch(void* const* d_in, const int* in_sizes, int n_in,
                              void* d_out, int out_size, void* d_ws, size_t ws_size,
                              hipStream_t stream) {
  const float* x  = (const float*)d_in[0];
  const float* wr = (const float*)d_in[1];
  const float* wi = (const float*)d_in[2];
  const float* wj = (const float*)d_in[3];
  const float* wk = (const float*)d_in[4];
  const float* bx = (const float*)d_in[5];
  // d_in[6..9] = uh_* are dead (h0 == 0)
  const float* fw = (const float*)d_in[10];
  const float* fb = (const float*)d_in[11];
  char* ws = (char*)d_ws;
  unsigned short* Wp  = (unsigned short*)(ws + WS_WP);
  unsigned short* Fp  = (unsigned short*)(ws + WS_FCO);
  float*          bp  = (float*)(ws + WS_BP);
  unsigned short* hvp = (unsigned short*)(ws + WS_HVP);
  float*          out = (float*)d_out;

  hipLaunchKernelGGL(pack_k,  dim3(416),    dim3(256), 0, stream, wr, wi, wj, wk, bx, fw, Wp, Fp, bp);
  hipLaunchKernelGGL(gemm1_k, dim3(256, 4), dim3(256), 0, stream, x, Wp, bp, hvp);
  hipLaunchKernelGGL(gemm2_k, dim3(256, 2), dim3(256), 0, stream, hvp, Fp, fb, out);
}

// Round 2
// 287.044 us; speedup vs baseline: 1.1428x; 1.1428x over previous
//
#include <hip/hip_runtime.h>
#include <cstdint>
#include <cstddef>

// ---------------- workspace layout (bytes) ----------------
// Wp   : packed gate-interleaved weight, bf16, 768x1024 (4 cb x 32 kb tiles, 192x32) = 1,572,864
// Fp   : packed fco_w, bf16, 256x256 (2 nb x 8 kb tiles, 128x32)                     =   131,072
// bp   : permuted bias (c = h*3+g), f32, 768
// hvp  : packed hidden vector, bf16, 32768x256 (256 mb x 8 kb tiles, 128x32)
#define WS_WP   0
#define WS_FCO  1572864
#define WS_BP   1703936
#define WS_HVP  1707008

typedef __attribute__((ext_vector_type(8))) __bf16 bf16x8;
typedef __attribute__((ext_vector_type(4))) __bf16 bf16x4;
typedef __attribute__((ext_vector_type(4))) float floatx4;

__device__ __forceinline__ unsigned short f2bf(float f) {
  unsigned int u = __builtin_bit_cast(unsigned int, f);
  u += 0x7fffu + ((u >> 16) & 1u);   // RNE
  return (unsigned short)(u >> 16);
}

__device__ __forceinline__ float sigmf(float z) {
  return __builtin_amdgcn_rcpf(1.f + __expf(-z));
}
__device__ __forceinline__ float tanh_(float z) {
  return 1.f - 2.f * __builtin_amdgcn_rcpf(1.f + __expf(2.f * z));
}

__device__ __forceinline__ void gld16(const void* g, void* l) {
  __builtin_amdgcn_global_load_lds(
      (const __attribute__((address_space(1))) unsigned int*)g,
      (__attribute__((address_space(3))) unsigned int*)l, 16, 0, 0);
}

// ---------------- merged pack kernel (unchanged) ----------------
__global__ __launch_bounds__(256) void pack_k(
    const float* __restrict__ wr, const float* __restrict__ wi,
    const float* __restrict__ wj, const float* __restrict__ wk,
    const float* __restrict__ bx, const float* __restrict__ fw,
    unsigned short* __restrict__ Wp, unsigned short* __restrict__ Fp,
    float* __restrict__ bp) {
  int t = threadIdx.x;
  if (blockIdx.x < 384) {
    int gpp = blockIdx.x >> 7;        // 0..2 -> gates {input,output,cell}
    int oct = blockIdx.x & 127;       // f-octet
    int gp = gpp + 1;                 // skip dead forget gate
    int h = t;                        // 0..255, lane-contiguous
    int hb = h >> 6, hr = h & 63;     // hb wave-uniform
    int f0 = oct << 3;
    int fb = f0 >> 8, fr0 = f0 & 255;
    const int   comp_t[4][4] = {{0,1,2,3},{1,0,3,2},{2,3,0,1},{3,2,1,0}};
    const float sign_t[4][4] = {{1.f,-1.f,-1.f,-1.f},{1.f,1.f,-1.f,1.f},
                                {1.f,1.f,1.f,-1.f},{1.f,-1.f,1.f,1.f}};
    const float* srcs[4] = {wr, wi, wj, wk};
    const float* s = srcs[comp_t[hb][fb]] + ((size_t)((gp << 8) + fr0)) * 64 + hr;
    float sg = sign_t[hb][fb];
    unsigned short v[8];
#pragma unroll
    for (int j = 0; j < 8; ++j) v[j] = f2bf(sg * s[(size_t)j * 64]);
    int c = h * 3 + gpp;
    int cb = c / 192, nl = c % 192;
    int kb = oct >> 2, q = oct & 3;
    int idx16 = (nl << 2) + (q ^ ((nl >> 1) & 3));
    uint4 val = make_uint4(
        (unsigned)v[0] | ((unsigned)v[1] << 16), (unsigned)v[2] | ((unsigned)v[3] << 16),
        (unsigned)v[4] | ((unsigned)v[5] << 16), (unsigned)v[6] | ((unsigned)v[7] << 16));
    *(uint4*)(Wp + (size_t)(cb * 32 + kb) * 6144 + idx16 * 8) = val;
    if (oct == 0) bp[c] = bx[(gp << 8) + h];
  } else {
    int oct = blockIdx.x - 384;       // k-octet 0..31
    int n = t;
    int k0 = oct << 3;
    unsigned short v[8];
#pragma unroll
    for (int j = 0; j < 8; ++j) v[j] = f2bf(fw[(size_t)(k0 + j) * 256 + n]);
    int nb = n >> 7, nl = n & 127, kb = oct >> 2, q = oct & 3;
    int idx16 = (nl << 2) + (q ^ ((nl >> 1) & 3));
    uint4 val = make_uint4(
        (unsigned)v[0] | ((unsigned)v[1] << 16), (unsigned)v[2] | ((unsigned)v[3] << 16),
        (unsigned)v[4] | ((unsigned)v[5] << 16), (unsigned)v[6] | ((unsigned)v[7] << 16));
    *(uint4*)(Fp + (size_t)((nb << 3) + kb) * 4096 + idx16 * 8) = val;
  }
}

// ---------------- GEMM1 + fused LSTM gates ----------------
// Tile 128x192, 4 waves of 64x96, BK=32, acc[4][6].
// THEORY (this revision): both prior versions are stall-bound by the per-iter
// vmcnt(0)+lgkmcnt(0) drain that __syncthreads emits (2-phase structure, guide
// T3/T4). New schedule: TRIPLE-buffered LDS (3 x 20 KB: A bf16 8K + B bf16 12K),
// staging issued 2 iterations ahead, raw s_barrier + counted s_waitcnt vmcnt(7)
// -- never drained to 0 in the main loop. Invariant at top of iter kt:
//   - buf[kt%3] fully staged (A written, B landed)
//   - 7 vmem in flight for kt+1: 4 A float4 reg-loads (RC) + 3 B gld_lds
// Body: issue 7 for kt+2 -> compute buf[kt%3] -> vmcnt(7) (kt+1 data arrived,
// ~2 compute phases of latency cover) -> WRITE_A(RC -> buf[(kt+1)%3]) ->
// lgkmcnt(0) -> s_barrier. compute/A-write/B-stage hit 3 distinct buffers mod 3;
// the single barrier per iter protects all cross-wave WAR/RAW hazards.
__global__ __launch_bounds__(256, 2) void gemm1_k(
    const float* __restrict__ x, const unsigned short* __restrict__ Wp,
    const float* __restrict__ bp, unsigned short* __restrict__ hvp) {
  __shared__ char smem[61440];                  // 3 x 20 KB; epilogue reuses 25.7 KB
  float* zep = (float*)smem;

  const int t = threadIdx.x;
  const int lane = t & 63, wid = t >> 6;
  const int wm = wid >> 1, wn = wid & 1;
  const int lrow = lane & 15, q = lane >> 4;
  const int rowt = blockIdx.x;                  // 0..255 (fast dim: W stays L2-hot)
  const int cby = blockIdx.y;                   // 0..3, 192 interleaved cols (64 h)
  const int row0 = rowt * 128;
  const float* xbase = x + (size_t)row0 * 1024;
  const unsigned short* wpb = Wp + (size_t)cby * 32 * 6144;

  // A staging mapping: thread t handles, for i in 0..3, the float4 at
  // row (i*32 + (t>>3)), k-quad (t&7). Per instr each 8-lane group covers one
  // 128B row segment (perfect coalescing).
  const int sr = t >> 3, skq = t & 7;
  const int sq8 = skq >> 1, shalf = skq & 1;

  floatx4 acc[4][6];
#pragma unroll
  for (int i = 0; i < 4; ++i)
#pragma unroll
    for (int j = 0; j < 6; ++j) acc[i][j] = (floatx4){0.f, 0.f, 0.f, 0.f};

#define STAGE_B(bufi, kt)                                                     \
  {                                                                           \
    unsigned short* sBs_ = (unsigned short*)(smem + (bufi) * 20480 + 8192);   \
    const unsigned short* bt_ = wpb + (size_t)(kt) * 6144;                    \
    _Pragma("unroll")                                                         \
    for (int i_ = 0; i_ < 3; ++i_) {                                          \
      int s_ = t + i_ * 256;                                                  \
      gld16(bt_ + s_ * 8, sBs_ + s_ * 8);                                     \
    }                                                                         \
  }
#define LOAD_A(ra, kt)                                                        \
  {                                                                           \
    const float* ab_ = xbase + (kt) * 32 + skq * 4;                           \
    _Pragma("unroll")                                                         \
    for (int i_ = 0; i_ < 4; ++i_)                                            \
      ra[i_] = *(const float4*)(ab_ + (size_t)(i_ * 32 + sr) * 1024);         \
  }
#define WRITE_A(ra, bufi)                                                     \
  {                                                                           \
    unsigned short* sAs_ = (unsigned short*)(smem + (bufi) * 20480);          \
    _Pragma("unroll")                                                         \
    for (int i_ = 0; i_ < 4; ++i_) {                                          \
      int m_ = i_ * 32 + sr;                                                  \
      int slot_ = (m_ << 2) + (sq8 ^ ((m_ >> 1) & 3));                        \
      bf16x4 v_;                                                              \
      v_[0] = (__bf16)ra[i_].x; v_[1] = (__bf16)ra[i_].y;                     \
      v_[2] = (__bf16)ra[i_].z; v_[3] = (__bf16)ra[i_].w;                     \
      *(bf16x4*)(sAs_ + slot_ * 8 + shalf * 4) = v_;                          \
    }                                                                         \
  }
#define COMPUTE(bufi)                                                         \
  {                                                                           \
    const unsigned short* sA_ = (const unsigned short*)(smem + (bufi) * 20480);\
    const unsigned short* sB_ = sA_ + 4096;                                   \
    bf16x8 af[4], bf[6];                                                      \
    _Pragma("unroll")                                                         \
    for (int mt = 0; mt < 4; ++mt) {                                          \
      int m = wm * 64 + mt * 16 + lrow;                                       \
      int slot = (m << 2) + (q ^ ((m >> 1) & 3));                             \
      af[mt] = *(const bf16x8*)(const void*)(sA_ + slot * 8);                 \
    }                                                                         \
    _Pragma("unroll")                                                         \
    for (int nt = 0; nt < 6; ++nt) {                                          \
      int n = wn * 96 + nt * 16 + lrow;                                       \
      int off16 = (n << 2) + (q ^ ((n >> 1) & 3));                            \
      bf[nt] = *(const bf16x8*)(const void*)(sB_ + off16 * 8);                \
    }                                                                         \
    _Pragma("unroll")                                                         \
    for (int mt = 0; mt < 4; ++mt)                                            \
      _Pragma("unroll")                                                       \
      for (int nt = 0; nt < 6; ++nt)                                          \
        acc[mt][nt] = __builtin_amdgcn_mfma_f32_16x16x32_bf16(                \
            af[mt], bf[nt], acc[mt][nt], 0, 0, 0);                            \
  }
// BODY: RC holds A(kt+1) (loads in flight or arrived); RN receives A(kt+2).
#define BODY(kt, RC, RN)                                                      \
  {                                                                           \
    if ((kt) < 30) {                                                          \
      LOAD_A(RN, (kt) + 2)                                                    \
      STAGE_B(((kt) + 2) % 3, (kt) + 2)                                       \
    }                                                                         \
    COMPUTE((kt) % 3)                                                         \
    if ((kt) < 30) {                                                          \
      asm volatile("s_waitcnt vmcnt(7)" ::: "memory");                        \
    } else {                                                                  \
      asm volatile("s_waitcnt vmcnt(0)" ::: "memory");                        \
    }                                                                         \
    if ((kt) < 31) { WRITE_A(RC, ((kt) + 1) % 3) }                            \
    asm volatile("s_waitcnt lgkmcnt(0)" ::: "memory");                        \
    __builtin_amdgcn_s_barrier();                                             \
    asm volatile("" ::: "memory");                                            \
  }

  float4 raA[4], raB[4];
  // Prologue: raA=A(0), raB=A(1); B(0)->buf0, B(1)->buf1; A(0) written to buf0.
  LOAD_A(raA, 0)
  STAGE_B(0, 0)
  LOAD_A(raB, 1)
  STAGE_B(1, 1)
  WRITE_A(raA, 0)                               // compiler waits raA's vmem
  asm volatile("s_waitcnt vmcnt(7)" ::: "memory");   // B(0) landed; raB+B(1) in flight
  asm volatile("s_waitcnt lgkmcnt(0)" ::: "memory");
  __builtin_amdgcn_s_barrier();
  asm volatile("" ::: "memory");

  for (int kt2 = 0; kt2 < 32; kt2 += 2) {
    BODY(kt2, raB, raA)                         // even kt: consume raB=A(kt+1 odd)
    BODY(kt2 + 1, raA, raB)                     // odd kt: consume raA=A(kt+1 even)
  }
#undef BODY
#undef COMPUTE
#undef STAGE_B
#undef LOAD_A
#undef WRITE_A
  __syncthreads();                              // all K-loop LDS reads done before zep reuse

  // Epilogue: 4 passes of 32 rows via LDS (pitch 201 f32), fused gates,
  // hv stored in gemm2's packed-swizzled tile layout.
  const float* bp0 = bp + cby * 192;
  const int er = t >> 3, oc = t & 7;
#pragma unroll
  for (int pass = 0; pass < 4; ++pass) {
    if (wm == (pass >> 1)) {
      int mtb = (pass & 1) * 2;
#pragma unroll
      for (int mi = 0; mi < 2; ++mi)
#pragma unroll
        for (int nt = 0; nt < 6; ++nt)
#pragma unroll
          for (int r = 0; r < 4; ++r)
            zep[(mi * 16 + q * 4 + r) * 201 + wn * 96 + nt * 16 + lrow] = acc[mtb + mi][nt][r];
    }
    __syncthreads();
    {
      int ml = pass * 32 + er;                  // local row 0..127
      unsigned short v[8];
#pragma unroll
      for (int j = 0; j < 8; ++j) {
        int hl = oc * 8 + j;                    // 0..63 local h
        float zi = zep[er * 201 + hl * 3 + 0] + bp0[hl * 3 + 0];
        float zo = zep[er * 201 + hl * 3 + 1] + bp0[hl * 3 + 1];
        float zc = zep[er * 201 + hl * 3 + 2] + bp0[hl * 3 + 2];
        float it = sigmf(zi);
        float ot = sigmf(zo);
        float cc = it * tanh_(zc);
        v[j] = f2bf(ot * tanh_(cc));
      }
      int ktile = cby * 2 + (oc >> 2), qq = oc & 3;
      int idx16 = (ml << 2) + (qq ^ ((ml >> 1) & 3));
      uint4 val = make_uint4(
          (unsigned)v[0] | ((unsigned)v[1] << 16), (unsigned)v[2] | ((unsigned)v[3] << 16),
          (unsigned)v[4] | ((unsigned)v[5] << 16), (unsigned)v[6] | ((unsigned)v[7] << 16));
      *(uint4*)(hvp + (size_t)(rowt * 8 + ktile) * 4096 + idx16 * 8) = val;
    }
    __syncthreads();
  }
}

// ---------------- GEMM2: out = hv @ fco_w + fco_b (fp32 output, unchanged) ----------------
__global__ __launch_bounds__(256, 4) void gemm2_k(
    const unsigned short* __restrict__ hvp, const unsigned short* __restrict__ Fp,
    const float* __restrict__ fcob, float* __restrict__ out) {
  __shared__ unsigned short sB[32768];          // 64 KB: 8 k-tiles of 128x32
  const int t = threadIdx.x;
  const int lane = t & 63, wid = t >> 6;
  const int wm = wid >> 1, wn = wid & 1;
  const int lrow = lane & 15, q = lane >> 4;
  const int mb = blockIdx.x, nb = blockIdx.y;

  const unsigned short* fpb = Fp + (size_t)nb * 32768;
#pragma unroll
  for (int i = 0; i < 16; ++i) gld16(fpb + (t + i * 256) * 8, sB + (t + i * 256) * 8);

  floatx4 acc[4][4];
#pragma unroll
  for (int i = 0; i < 4; ++i)
#pragma unroll
    for (int j = 0; j < 4; ++j) acc[i][j] = (floatx4){0.f, 0.f, 0.f, 0.f};
  __syncthreads();

#pragma unroll
  for (int kt = 0; kt < 8; ++kt) {
    const unsigned short* at_ = hvp + (size_t)(mb * 8 + kt) * 4096;
    bf16x8 af[4], bf[4];
#pragma unroll
    for (int mt = 0; mt < 4; ++mt) {
      int m = wm * 64 + mt * 16 + lrow;
      int o = (m << 2) + (q ^ ((m >> 1) & 3));
      af[mt] = *(const bf16x8*)(const void*)(at_ + o * 8);    // global, coalesced
    }
#pragma unroll
    for (int nt = 0; nt < 4; ++nt) {
      int n = wn * 64 + nt * 16 + lrow;
      int o = (n << 2) + (q ^ ((n >> 1) & 3));
      bf[nt] = *(const bf16x8*)(const void*)(sB + kt * 4096 + o * 8);
    }
#pragma unroll
    for (int mt = 0; mt < 4; ++mt)
#pragma unroll
      for (int nt = 0; nt < 4; ++nt)
        acc[mt][nt] = __builtin_amdgcn_mfma_f32_16x16x32_bf16(af[mt], bf[nt], acc[mt][nt], 0, 0, 0);
  }
#pragma unroll
  for (int nt = 0; nt < 4; ++nt) {
    int colg = nb * 128 + wn * 64 + nt * 16 + lrow;
    float bias = fcob[colg];
#pragma unroll
    for (int mt = 0; mt < 4; ++mt) {
      int rowg = mb * 128 + wm * 64 + mt * 16 + q * 4;
#pragma unroll
      for (int r = 0; r < 4; ++r)
        out[(size_t)(rowg + r) * 256 + colg] = acc[mt][nt][r] + bias;
    }
  }
}

extern "C" void kernel_launch(void* const* d_in, const int* in_sizes, int n_in,
                              void* d_out, int out_size, void* d_ws, size_t ws_size,
                              hipStream_t stream) {
  const float* x  = (const float*)d_in[0];
  const float* wr = (const float*)d_in[1];
  const float* wi = (const float*)d_in[2];
  const float* wj = (const float*)d_in[3];
  const float* wk = (const float*)d_in[4];
  const float* bx = (const float*)d_in[5];
  // d_in[6..9] = uh_* are dead (h0 == 0)
  const float* fw = (const float*)d_in[10];
  const float* fb = (const float*)d_in[11];
  char* ws = (char*)d_ws;
  unsigned short* Wp  = (unsigned short*)(ws + WS_WP);
  unsigned short* Fp  = (unsigned short*)(ws + WS_FCO);
  float*          bp  = (float*)(ws + WS_BP);
  unsigned short* hvp = (unsigned short*)(ws + WS_HVP);
  float*          out = (float*)d_out;

  hipLaunchKernelGGL(pack_k,  dim3(416),    dim3(256), 0, stream, wr, wi, wj, wk, bx, fw, Wp, Fp, bp);
  hipLaunchKernelGGL(gemm1_k, dim3(256, 4), dim3(256), 0, stream, x, Wp, bp, hvp);
  hipLaunchKernelGGL(gemm2_k, dim3(256, 2), dim3(256), 0, stream, hvp, Fp, fb, out);
}